// Round 1
// baseline (248.448 us; speedup 1.0000x reference)
//
#include <hip/hip_runtime.h>
#include <cstdint>

#define BB 4
#define NN 2048
#define NH 4
#define FH 64   // hidden feats per head
#define FO 32   // output feats
#define NW (NN/32)  // mask words per row = 64

typedef __attribute__((ext_vector_type(8))) short bf16x8;
typedef __attribute__((ext_vector_type(4))) float f32x4;
typedef __attribute__((ext_vector_type(4))) unsigned short u16x4;

__device__ __forceinline__ short f2bf(float f) {
  unsigned u = __float_as_uint(f);
  u = (u + 0x7FFFu + ((u >> 16) & 1u)) >> 16;   // RNE, no NaN inputs here
  return (short)u;
}
__device__ __forceinline__ float bf2f(short s) {
  return __uint_as_float(((unsigned)(unsigned short)s) << 16);
}
__device__ __forceinline__ float lrelu(float s) { return s > 0.f ? s : 0.2f * s; }

// ---------------- K0: pack adj (int32 0/1) into bitmask ----------------
__global__ __launch_bounds__(256) void k0_pack(const int* __restrict__ adj,
                                               unsigned* __restrict__ mb) {
  int gid = blockIdx.x * 256 + threadIdx.x;          // one int4 per thread
  const int4 v = ((const int4*)adj)[gid];
  unsigned nib = (unsigned)(v.x != 0) | ((unsigned)(v.y != 0) << 1) |
                 ((unsigned)(v.z != 0) << 2) | ((unsigned)(v.w != 0) << 3);
  unsigned wv = nib << (4 * (threadIdx.x & 7));
  wv |= __shfl_xor(wv, 1);
  wv |= __shfl_xor(wv, 2);
  wv |= __shfl_xor(wv, 4);
  if ((threadIdx.x & 7) == 0) mb[gid >> 3] = wv;
}

// ---------------- K1: Wh1 = x @ W1^T (per head), store Wh1^T bf16 + scores ----
__global__ __launch_bounds__(256) void k1_proj1(
    const float* __restrict__ x, const float* __restrict__ W1,
    const float* __restrict__ a1, unsigned short* __restrict__ wht1,
    float* __restrict__ ssrc_g, float* __restrict__ sdst_g) {
  int blk = blockIdx.x;          // 256 blocks: 32 rows each over B*N=8192
  int rowg = blk * 32;
  int b = rowg >> 11;
  int rloc = rowg & (NN - 1);
  int tid = threadIdx.x;
  int lane = tid & 63;
  int h = tid >> 6;              // wave = head
  int cl = lane & 15, g = lane >> 4;

  // A fragments: x rows (m = cl, k = 8g+e), f32 -> bf16
  bf16x8 af[2][2];
#pragma unroll
  for (int st = 0; st < 2; ++st) {
    const float* xr = x + (size_t)(rowg + st * 16 + cl) * 64;
#pragma unroll
    for (int ks = 0; ks < 2; ++ks) {
      f32x4 v0 = *(const f32x4*)(xr + ks * 32 + 8 * g);
      f32x4 v1 = *(const f32x4*)(xr + ks * 32 + 8 * g + 4);
      bf16x8 a;
#pragma unroll
      for (int e = 0; e < 4; ++e) { a[e] = f2bf(v0[e]); a[4 + e] = f2bf(v1[e]); }
      af[st][ks] = a;
    }
  }
  f32x4 zero = {0.f, 0.f, 0.f, 0.f};
  f32x4 acc[2][4];
#pragma unroll
  for (int st = 0; st < 2; ++st)
#pragma unroll
    for (int ft = 0; ft < 4; ++ft) acc[st][ft] = zero;

#pragma unroll
  for (int ft = 0; ft < 4; ++ft) {
    const float* wr = W1 + (size_t)(h * FH + ft * 16 + cl) * 64;  // W1[h][col][k]
#pragma unroll
    for (int ks = 0; ks < 2; ++ks) {
      f32x4 v0 = *(const f32x4*)(wr + ks * 32 + 8 * g);
      f32x4 v1 = *(const f32x4*)(wr + ks * 32 + 8 * g + 4);
      bf16x8 bfr;
#pragma unroll
      for (int e = 0; e < 4; ++e) { bfr[e] = f2bf(v0[e]); bfr[4 + e] = f2bf(v1[e]); }
      acc[0][ft] = __builtin_amdgcn_mfma_f32_16x16x32_bf16(af[0][ks], bfr, acc[0][ft], 0, 0, 0);
      acc[1][ft] = __builtin_amdgcn_mfma_f32_16x16x32_bf16(af[1][ks], bfr, acc[1][ft], 0, 0, 0);
    }
  }
  float as[4], ad[4];
#pragma unroll
  for (int ft = 0; ft < 4; ++ft) {
    as[ft] = a1[h * 128 + ft * 16 + cl];
    ad[ft] = a1[h * 128 + 64 + ft * 16 + cl];
  }
#pragma unroll
  for (int st = 0; st < 2; ++st) {
    float ps[4] = {0.f, 0.f, 0.f, 0.f}, pd[4] = {0.f, 0.f, 0.f, 0.f};
#pragma unroll
    for (int ft = 0; ft < 4; ++ft) {
      u16x4 w4;
#pragma unroll
      for (int r = 0; r < 4; ++r) {
        float v = acc[st][ft][r];                    // row = rloc+st*16+4g+r, col = ft*16+cl
        w4[r] = (unsigned short)f2bf(v);
        ps[r] += v * as[ft];
        pd[r] += v * ad[ft];
      }
      int col = ft * 16 + cl;
      *(u16x4*)(wht1 + (size_t)((b * NH + h) * FH + col) * NN + rloc + st * 16 + 4 * g) = w4;
    }
#pragma unroll
    for (int r = 0; r < 4; ++r) {
      float s = ps[r], d = pd[r];
      s += __shfl_xor(s, 1); s += __shfl_xor(s, 2); s += __shfl_xor(s, 4); s += __shfl_xor(s, 8);
      d += __shfl_xor(d, 1); d += __shfl_xor(d, 2); d += __shfl_xor(d, 4); d += __shfl_xor(d, 8);
      if (cl == 0) {
        int rr = rloc + st * 16 + 4 * g + r;
        ssrc_g[(b * NH + h) * NN + rr] = s;
        sdst_g[(b * NH + h) * NN + rr] = d;
      }
    }
  }
}

// ---------------- K2: layer-1 attention, 4 heads/block, 32 rows, ELU, concat ----
__global__ __launch_bounds__(256) void k2_attn1(
    const unsigned short* __restrict__ wht1,
    const float* __restrict__ ssrc_g, const float* __restrict__ sdst_g,
    const unsigned* __restrict__ mb, float* __restrict__ hout) {
  __shared__ f32x4 sdl[NH][NN / 4];   // 32 KB: s_dst per head
  int blk = blockIdx.x;               // 256 blocks
  int b = blk >> 6;
  int rowbase = (blk & 63) << 5;
  int tid = threadIdx.x;
  int lane = tid & 63;
  int h = tid >> 6;
  int cl = lane & 15, g = lane >> 4;

  const f32x4* sd4 = (const f32x4*)(sdst_g + (b * NH + h) * NN);
  float mx = -1e30f;
#pragma unroll
  for (int it = 0; it < 8; ++it) {
    f32x4 v = sd4[it * 64 + lane];
    sdl[h][it * 64 + lane] = v;
    mx = fmaxf(fmaxf(mx, v[0]), fmaxf(v[1], fmaxf(v[2], v[3])));
  }
  mx = fmaxf(mx, __shfl_xor(mx, 1));  mx = fmaxf(mx, __shfl_xor(mx, 2));
  mx = fmaxf(mx, __shfl_xor(mx, 4));  mx = fmaxf(mx, __shfl_xor(mx, 8));
  mx = fmaxf(mx, __shfl_xor(mx, 16)); mx = fmaxf(mx, __shfl_xor(mx, 32));
  __syncthreads();

  float ssr0 = ssrc_g[(b * NH + h) * NN + rowbase + cl];
  float ssr1 = ssrc_g[(b * NH + h) * NN + rowbase + 16 + cl];
  float m0 = lrelu(ssr0 + mx), m1 = lrelu(ssr1 + mx);  // per-row softmax shift (upper bound)

  f32x4 zero = {0.f, 0.f, 0.f, 0.f};
  f32x4 acc[2][4];
#pragma unroll
  for (int st = 0; st < 2; ++st)
#pragma unroll
    for (int ft = 0; ft < 4; ++ft) acc[st][ft] = zero;
  float d0 = 0.f, d1 = 0.f;

  const unsigned* mr0 = mb + (size_t)(b * NN + rowbase + cl) * NW;
  const unsigned* mr1 = mr0 + 16 * NW;
  const unsigned short* whb = wht1 + (size_t)((b * NH + h) * FH) * NN;

  for (int kb = 0; kb < NW; ++kb) {
    unsigned by0 = (mr0[kb] >> (8 * g)) & 0xFFu;
    unsigned by1 = (mr1[kb] >> (8 * g)) & 0xFFu;
    f32x4 sv0 = sdl[h][kb * 8 + 2 * g];
    f32x4 sv1 = sdl[h][kb * 8 + 2 * g + 1];
    bf16x8 pa, pb;
    float dd0 = 0.f, dd1 = 0.f;
#pragma unroll
    for (int e = 0; e < 8; ++e) {
      float sdv = (e < 4) ? sv0[e] : sv1[e - 4];
      float s0 = ssr0 + sdv;
      float w0 = ((by0 >> e) & 1u) ? __expf(lrelu(s0) - m0) : 0.f;
      short q0 = f2bf(w0);
      dd0 += bf2f(q0);                 // denom from ROUNDED weights (consistency)
      pa[e] = q0;
      float s1 = ssr1 + sdv;
      float w1 = ((by1 >> e) & 1u) ? __expf(lrelu(s1) - m1) : 0.f;
      short q1 = f2bf(w1);
      dd1 += bf2f(q1);
      pb[e] = q1;
    }
    d0 += dd0; d1 += dd1;
#pragma unroll
    for (int ft = 0; ft < 4; ++ft) {
      bf16x8 bf = *(const bf16x8*)(whb + (size_t)(ft * 16 + cl) * NN + kb * 32 + 8 * g);
      acc[0][ft] = __builtin_amdgcn_mfma_f32_16x16x32_bf16(pa, bf, acc[0][ft], 0, 0, 0);
      acc[1][ft] = __builtin_amdgcn_mfma_f32_16x16x32_bf16(pb, bf, acc[1][ft], 0, 0, 0);
    }
  }
  d0 += __shfl_xor(d0, 16); d0 += __shfl_xor(d0, 32);  // lane holds denom of row (lane&15)
  d1 += __shfl_xor(d1, 16); d1 += __shfl_xor(d1, 32);

#pragma unroll
  for (int st = 0; st < 2; ++st) {
#pragma unroll
    for (int r = 0; r < 4; ++r) {
      int rowm = 4 * g + r;                             // D row = (lane>>4)*4 + reg
      float dd = __shfl(st == 0 ? d0 : d1, rowm);
      float inv = 1.f / dd;
      int row = rowbase + st * 16 + rowm;
#pragma unroll
      for (int ft = 0; ft < 4; ++ft) {
        float v = acc[st][ft][r] * inv;
        v = v > 0.f ? v : (__expf(v) - 1.f);            // ELU (concat layer)
        hout[(size_t)(b * NN + row) * (NH * FH) + h * FH + ft * 16 + cl] = v;
      }
    }
  }
}

// ---------------- K3: Wh2 = h @ W2^T, store Wh2^T bf16 + scores ----------------
__global__ __launch_bounds__(256) void k3_proj2(
    const float* __restrict__ hin, const float* __restrict__ W2,
    const float* __restrict__ a2, unsigned short* __restrict__ wh2t,
    float* __restrict__ ssrc_g, float* __restrict__ sdst_g) {
  __shared__ f32x4 hl[64 * 64];  // 64 KB, XOR-swizzled columns
  int blk = blockIdx.x;          // 128 blocks: 64 nodes each
  int b = blk >> 5;
  int nodebase = (blk & 31) << 6;
  int t = threadIdx.x;
  const f32x4* src = (const f32x4*)(hin + (size_t)(b * NN + nodebase) * 256);
#pragma unroll
  for (int it = 0; it < 16; ++it) {
    int row = it * 4 + (t >> 6);
    int c4 = t & 63;
    hl[row * 64 + (c4 ^ (row & 15))] = src[row * 64 + c4];
  }
  __syncthreads();
  int node = t >> 2, q = t & 3;
  float acc[8];
#pragma unroll
  for (int ff = 0; ff < 8; ++ff) {
    int f = q * 8 + ff;
    const f32x4* wr = (const f32x4*)(W2 + f * 256);
    float a = 0.f;
#pragma unroll 8
    for (int i4 = 0; i4 < 64; ++i4) {
      f32x4 wv = wr[i4];
      f32x4 hv = hl[node * 64 + (i4 ^ (node & 15))];
      a += wv[0] * hv[0] + wv[1] * hv[1] + wv[2] * hv[2] + wv[3] * hv[3];
    }
    acc[ff] = a;
  }
  float ps = 0.f, pd = 0.f;
#pragma unroll
  for (int ff = 0; ff < 8; ++ff) {
    int f = q * 8 + ff;
    wh2t[(size_t)(b * FO + f) * NN + nodebase + node] = (unsigned short)f2bf(acc[ff]);
    ps += acc[ff] * a2[f];
    pd += acc[ff] * a2[32 + f];
  }
  ps += __shfl_xor(ps, 1); ps += __shfl_xor(ps, 2);
  pd += __shfl_xor(pd, 1); pd += __shfl_xor(pd, 2);
  if (q == 0) {
    ssrc_g[b * NN + nodebase + node] = ps;
    sdst_g[b * NN + nodebase + node] = pd;
  }
}

// ---------------- K4: layer-2 attention (single head, 32 feats, no ELU) --------
__global__ __launch_bounds__(256) void k4_attn2(
    const unsigned short* __restrict__ wh2t,
    const float* __restrict__ ssrc_g, const float* __restrict__ sdst_g,
    const unsigned* __restrict__ mb, float* __restrict__ outp) {
  __shared__ f32x4 sdl[NN / 4];   // 8 KB, shared by all waves
  __shared__ float wmax[4];
  int blk = blockIdx.x;           // 128 blocks: 64 rows each
  int b = blk >> 5;
  int rowbase = (blk & 31) << 6;
  int t = threadIdx.x, lane = t & 63, w = t >> 6;
  int cl = lane & 15, g = lane >> 4;

  const f32x4* sd4 = (const f32x4*)(sdst_g + b * NN);
  float mx = -1e30f;
#pragma unroll
  for (int it = 0; it < 2; ++it) {
    int i4 = it * 256 + t;
    f32x4 v = sd4[i4];
    sdl[i4] = v;
    mx = fmaxf(fmaxf(v[0], v[1]), fmaxf(fmaxf(v[2], v[3]), mx));
  }
  mx = fmaxf(mx, __shfl_xor(mx, 1));  mx = fmaxf(mx, __shfl_xor(mx, 2));
  mx = fmaxf(mx, __shfl_xor(mx, 4));  mx = fmaxf(mx, __shfl_xor(mx, 8));
  mx = fmaxf(mx, __shfl_xor(mx, 16)); mx = fmaxf(mx, __shfl_xor(mx, 32));
  if (lane == 0) wmax[w] = mx;
  __syncthreads();
  mx = fmaxf(fmaxf(wmax[0], wmax[1]), fmaxf(wmax[2], wmax[3]));

  int row = rowbase + w * 16 + cl;
  float ssr = ssrc_g[b * NN + row];
  float m = lrelu(ssr + mx);
  f32x4 zero = {0.f, 0.f, 0.f, 0.f};
  f32x4 acc[2];
  acc[0] = zero; acc[1] = zero;
  float dnm = 0.f;
  const unsigned* mr = mb + (size_t)(b * NN + row) * NW;
  const unsigned short* whb = wh2t + (size_t)(b * FO) * NN;

  for (int kb = 0; kb < NW; ++kb) {
    unsigned by0 = (mr[kb] >> (8 * g)) & 0xFFu;
    f32x4 sv0 = sdl[kb * 8 + 2 * g];
    f32x4 sv1 = sdl[kb * 8 + 2 * g + 1];
    bf16x8 pa;
    float dd = 0.f;
#pragma unroll
    for (int e = 0; e < 8; ++e) {
      float sdv = (e < 4) ? sv0[e] : sv1[e - 4];
      float s = ssr + sdv;
      float wv = ((by0 >> e) & 1u) ? __expf(lrelu(s) - m) : 0.f;
      short qv = f2bf(wv);
      dd += bf2f(qv);
      pa[e] = qv;
    }
    dnm += dd;
#pragma unroll
    for (int ft = 0; ft < 2; ++ft) {
      bf16x8 bf = *(const bf16x8*)(whb + (size_t)(ft * 16 + cl) * NN + kb * 32 + 8 * g);
      acc[ft] = __builtin_amdgcn_mfma_f32_16x16x32_bf16(pa, bf, acc[ft], 0, 0, 0);
    }
  }
  dnm += __shfl_xor(dnm, 16); dnm += __shfl_xor(dnm, 32);
#pragma unroll
  for (int r = 0; r < 4; ++r) {
    int rowm = 4 * g + r;
    float dd = __shfl(dnm, rowm);
    float inv = 1.f / dd;
#pragma unroll
    for (int ft = 0; ft < 2; ++ft) {
      float v = acc[ft][r] * inv;
      outp[(size_t)(b * NN + rowbase + w * 16 + rowm) * FO + ft * 16 + cl] = v;
    }
  }
}

extern "C" void kernel_launch(void* const* d_in, const int* in_sizes, int n_in,
                              void* d_out, int out_size, void* d_ws, size_t ws_size,
                              hipStream_t stream) {
  (void)in_sizes; (void)n_in; (void)out_size; (void)ws_size;
  const float* x   = (const float*)d_in[0];
  const int*   adj = (const int*)d_in[1];
  const float* W1  = (const float*)d_in[2];
  const float* a1  = (const float*)d_in[3];
  const float* W2  = (const float*)d_in[4];
  const float* a2  = (const float*)d_in[5];
  float* outp = (float*)d_out;
  char* ws = (char*)d_ws;

  unsigned*       mbits = (unsigned*)(ws);                                  // 2 MB
  unsigned short* wht1  = (unsigned short*)(ws + (size_t)(2u << 20));       // 4 MB
  float*          ssrc1 = (float*)(ws + (size_t)(6u << 20));                // 128 KB
  float*          sdst1 = (float*)(ws + (size_t)(6u << 20) + (128u << 10)); // 128 KB
  float*          hbuf  = (float*)(ws + (size_t)(6u << 20) + (256u << 10)); // 8 MB
  unsigned short* wh2t  = (unsigned short*)(ws + (size_t)(14u << 20) + (256u << 10)); // 512 KB
  float*          ssrc2 = (float*)(ws + (size_t)(14u << 20) + (768u << 10));          // 32 KB
  float*          sdst2 = (float*)(ws + (size_t)(14u << 20) + (800u << 10));          // 32 KB

  k0_pack <<<16384, 256, 0, stream>>>(adj, mbits);
  k1_proj1<<<256,   256, 0, stream>>>(x, W1, a1, wht1, ssrc1, sdst1);
  k2_attn1<<<256,   256, 0, stream>>>(wht1, ssrc1, sdst1, mbits, hbuf);
  k3_proj2<<<128,   256, 0, stream>>>(hbuf, W2, a2, wh2t, ssrc2, sdst2);
  k4_attn2<<<128,   256, 0, stream>>>(wh2t, ssrc2, sdst2, mbits, outp);
}

// Round 2
// 209.320 us; speedup vs baseline: 1.1869x; 1.1869x over previous
//
#include <hip/hip_runtime.h>
#include <hip/hip_bf16.h>
#include <cstdint>

#define NN 2048
#define NH 4
#define NW 64   // mask words per row

typedef __attribute__((ext_vector_type(8))) short bf16x8;
typedef __attribute__((ext_vector_type(4))) float f32x4;
typedef __attribute__((ext_vector_type(4))) unsigned short u16x4;

__device__ __forceinline__ float lrelu(float s) { return s > 0.f ? s : 0.2f * s; }

__device__ __forceinline__ unsigned pk2(float lo, float hi) {
  __hip_bfloat162 h2 = __float22bfloat162_rn(make_float2(lo, hi));
  union { __hip_bfloat162 h; unsigned u; } c; c.h = h2; return c.u;
}
__device__ __forceinline__ short f2bf1(float f) {
  __hip_bfloat16 h = __float2bfloat16(f);
  union { __hip_bfloat16 h; unsigned short u; } c; c.h = h; return (short)c.u;
}
__device__ __forceinline__ bf16x8 cvt8(f32x4 v0, f32x4 v1) {
  union { unsigned u[4]; bf16x8 v; } r;
  r.u[0] = pk2(v0[0], v0[1]); r.u[1] = pk2(v0[2], v0[3]);
  r.u[2] = pk2(v1[0], v1[1]); r.u[3] = pk2(v1[2], v1[3]);
  return r.v;
}

// ---------- kA: blocks [0,16384): pack adj bits; [16384,16896): proj1 ----------
__global__ __launch_bounds__(256) void kA(
    const int* __restrict__ adj, unsigned* __restrict__ mb,
    const float* __restrict__ x, const float* __restrict__ W1,
    const float* __restrict__ a1, unsigned short* __restrict__ wht1,
    float* __restrict__ ssrc1, float* __restrict__ G1g, float* __restrict__ G2g) {
  if (blockIdx.x < 16384) {
    int gid = blockIdx.x * 256 + threadIdx.x;       // one int4 per thread
    const int4 v = ((const int4*)adj)[gid];
    unsigned nib = (unsigned)(v.x != 0) | ((unsigned)(v.y != 0) << 1) |
                   ((unsigned)(v.z != 0) << 2) | ((unsigned)(v.w != 0) << 3);
    unsigned wv = nib << (4 * (threadIdx.x & 7));
    wv |= __shfl_xor(wv, 1); wv |= __shfl_xor(wv, 2); wv |= __shfl_xor(wv, 4);
    if ((threadIdx.x & 7) == 0) mb[gid >> 3] = wv;
    return;
  }
  int blk = blockIdx.x - 16384;        // 0..511, 16 rows each
  int rowg = blk * 16;
  int b = rowg >> 11, rloc = rowg & (NN - 1);
  int tid = threadIdx.x, lane = tid & 63, h = tid >> 6;
  int cl = lane & 15, g = lane >> 4;

  const float* xr = x + (size_t)(rowg + cl) * 64 + 8 * g;
  bf16x8 af[2];
#pragma unroll
  for (int ks = 0; ks < 2; ++ks)
    af[ks] = cvt8(*(const f32x4*)(xr + ks * 32), *(const f32x4*)(xr + ks * 32 + 4));

  f32x4 zero = {0.f, 0.f, 0.f, 0.f};
  f32x4 acc[4] = {zero, zero, zero, zero};
#pragma unroll
  for (int ft = 0; ft < 4; ++ft) {
    const float* wr = W1 + (size_t)(h * 64 + ft * 16 + cl) * 64 + 8 * g;
#pragma unroll
    for (int ks = 0; ks < 2; ++ks) {
      bf16x8 bfr = cvt8(*(const f32x4*)(wr + ks * 32), *(const f32x4*)(wr + ks * 32 + 4));
      acc[ft] = __builtin_amdgcn_mfma_f32_16x16x32_bf16(af[ks], bfr, acc[ft], 0, 0, 0);
    }
  }
  float ps[4] = {0.f, 0.f, 0.f, 0.f}, pd[4] = {0.f, 0.f, 0.f, 0.f};
#pragma unroll
  for (int ft = 0; ft < 4; ++ft) {
    float as = a1[h * 128 + ft * 16 + cl];
    float ad = a1[h * 128 + 64 + ft * 16 + cl];
    u16x4 w4;
#pragma unroll
    for (int r = 0; r < 4; ++r) {
      float v = acc[ft][r];                       // row rloc+4g+r, col ft*16+cl
      w4[r] = (unsigned short)f2bf1(v);
      ps[r] += v * as; pd[r] += v * ad;
    }
    *(u16x4*)(wht1 + (size_t)((b * NH + h) * 64 + ft * 16 + cl) * NN + rloc + 4 * g) = w4;
  }
#pragma unroll
  for (int r = 0; r < 4; ++r) {
    float s = ps[r], d = pd[r];
    s += __shfl_xor(s, 1); s += __shfl_xor(s, 2); s += __shfl_xor(s, 4); s += __shfl_xor(s, 8);
    d += __shfl_xor(d, 1); d += __shfl_xor(d, 2); d += __shfl_xor(d, 4); d += __shfl_xor(d, 8);
    if (cl == 0) {
      int idx = (b * NH + h) * NN + rloc + 4 * g + r;
      ssrc1[idx] = s;
      G1g[idx] = __expf(d);
      G2g[idx] = __expf(0.2f * d);
    }
  }
}

// ---------- k2: layer-1 attention. block = 1 head x 64 rows (4 waves x 16) ------
__global__ __launch_bounds__(256) void k2_attn1(
    const unsigned short* __restrict__ wht1, const float* __restrict__ ssrc1,
    const float* __restrict__ G1g, const float* __restrict__ G2g,
    const unsigned* __restrict__ mb, float* __restrict__ hout) {
  __shared__ unsigned sdm[NW][64];     // [word][row-in-block] 16 KB
  int blk = blockIdx.x;                // 512 = [b(4)][h(4)][tile(32)]
  int tile = blk & 31, bh = blk >> 5;
  int h = bh & 3, b = bh >> 2;
  int rowblk = tile << 6;
  int t = threadIdx.x, lane = t & 63, w = t >> 6;
  int cl = lane & 15, g = lane >> 4;

  { // stage 64 rows x 64 mask words
    int row = t >> 2, wb = (t & 3) * 16;
    const uint4* src = (const uint4*)(mb + (size_t)(b * NN + rowblk + row) * NW + wb);
#pragma unroll
    for (int i = 0; i < 4; ++i) {
      uint4 v = src[i];
      sdm[wb + 4 * i + 0][row] = v.x; sdm[wb + 4 * i + 1][row] = v.y;
      sdm[wb + 4 * i + 2][row] = v.z; sdm[wb + 4 * i + 3][row] = v.w;
    }
  }
  const float* G1 = G1g + (b * NH + h) * NN;
  const float* G2 = G2g + (b * NH + h) * NN;
  float mxG = 0.f;
#pragma unroll
  for (int it = 0; it < 8; ++it) {
    f32x4 v = ((const f32x4*)G1)[it * 64 + lane];
    mxG = fmaxf(fmaxf(mxG, v[0]), fmaxf(v[1], fmaxf(v[2], v[3])));
  }
  mxG = fmaxf(mxG, __shfl_xor(mxG, 1));  mxG = fmaxf(mxG, __shfl_xor(mxG, 2));
  mxG = fmaxf(mxG, __shfl_xor(mxG, 4));  mxG = fmaxf(mxG, __shfl_xor(mxG, 8));
  mxG = fmaxf(mxG, __shfl_xor(mxG, 16)); mxG = fmaxf(mxG, __shfl_xor(mxG, 32));

  int rowW = rowblk + w * 16;
  float s = ssrc1[(b * NH + h) * NN + rowW + cl];   // this lane's P-row
  float m = lrelu(s + __logf(mxG));                 // valid shift upper bound
  float F1 = __expf(s - m), F2 = __expf(0.2f * s - m), T = __expf(-s);
  __syncthreads();

  short onev = (cl == 0) ? (short)0x3F80 : (short)0;
  bf16x8 ones = {onev, onev, onev, onev, onev, onev, onev, onev};

  f32x4 zero = {0.f, 0.f, 0.f, 0.f};
  f32x4 acc[4] = {zero, zero, zero, zero};
  f32x4 acc1 = zero;                                // denominator via ones column
  const unsigned short* whb = wht1 + (size_t)((b * NH + h) * 64) * NN;
  int rloc = w * 16 + cl;

  for (int kb = 0; kb < NW; ++kb) {
    unsigned by = (sdm[kb][rloc] >> (8 * g)) & 0xFFu;
    int j0 = kb * 32 + 8 * g;
    f32x4 g1a = *(const f32x4*)(G1 + j0);
    f32x4 g1b = *(const f32x4*)(G1 + j0 + 4);
    f32x4 g2a = *(const f32x4*)(G2 + j0);
    f32x4 g2b = *(const f32x4*)(G2 + j0 + 4);
    float wv[8];
#pragma unroll
    for (int e = 0; e < 8; ++e) {
      float g1 = (e < 4) ? g1a[e] : g1b[e - 4];
      float g2 = (e < 4) ? g2a[e] : g2b[e - 4];
      bool sg = g1 > T;                             // <=> s + t_j > 0
      float val = (sg ? F1 : F2) * (sg ? g1 : g2);
      wv[e] = ((by >> e) & 1u) ? val : 0.f;
    }
    union { unsigned u[4]; bf16x8 v; } pa;
    pa.u[0] = pk2(wv[0], wv[1]); pa.u[1] = pk2(wv[2], wv[3]);
    pa.u[2] = pk2(wv[4], wv[5]); pa.u[3] = pk2(wv[6], wv[7]);
#pragma unroll
    for (int ft = 0; ft < 4; ++ft) {
      bf16x8 bf = *(const bf16x8*)(whb + (size_t)(ft * 16 + cl) * NN + j0);
      acc[ft] = __builtin_amdgcn_mfma_f32_16x16x32_bf16(pa.v, bf, acc[ft], 0, 0, 0);
    }
    acc1 = __builtin_amdgcn_mfma_f32_16x16x32_bf16(pa.v, ones, acc1, 0, 0, 0);
  }
#pragma unroll
  for (int r = 0; r < 4; ++r) {
    float dd = __shfl(acc1[r], lane & 48);          // denom lives at cl==0 of same g
    float inv = 1.f / dd;
    int row = rowW + 4 * g + r;
    float* dst = hout + (size_t)(b * NN + row) * 256 + h * 64;
#pragma unroll
    for (int ft = 0; ft < 4; ++ft) {
      float v = acc[ft][r] * inv;
      v = v > 0.f ? v : (__expf(v) - 1.f);          // ELU
      dst[ft * 16 + cl] = v;
    }
  }
}

// ---------- k3: Wh2 = h @ W2^T via MFMA split-K; scores + G factors ------------
__global__ __launch_bounds__(256) void k3_proj2(
    const float* __restrict__ hin, const float* __restrict__ W2,
    const float* __restrict__ a2, unsigned short* __restrict__ wh2t,
    float* __restrict__ ssrc2, float* __restrict__ G1o, float* __restrict__ G2o) {
  __shared__ float cmb[4][16][33];
  int blk = blockIdx.x;                 // 512: 16 rows each
  int b = blk >> 7, rowbase = (blk & 127) << 4;
  int t = threadIdx.x, lane = t & 63, w = t >> 6;
  int cl = lane & 15, g = lane >> 4;
  int k0 = w * 64;                      // K split across 4 waves

  const float* hr = hin + (size_t)(b * NN + rowbase + cl) * 256 + k0 + 8 * g;
  bf16x8 af[2];
#pragma unroll
  for (int ks = 0; ks < 2; ++ks)
    af[ks] = cvt8(*(const f32x4*)(hr + ks * 32), *(const f32x4*)(hr + ks * 32 + 4));

  f32x4 zero = {0.f, 0.f, 0.f, 0.f};
  f32x4 acc[2] = {zero, zero};
#pragma unroll
  for (int ft = 0; ft < 2; ++ft) {
    const float* wr = W2 + (size_t)(ft * 16 + cl) * 256 + k0 + 8 * g;
#pragma unroll
    for (int ks = 0; ks < 2; ++ks) {
      bf16x8 bfr = cvt8(*(const f32x4*)(wr + ks * 32), *(const f32x4*)(wr + ks * 32 + 4));
      acc[ft] = __builtin_amdgcn_mfma_f32_16x16x32_bf16(af[ks], bfr, acc[ft], 0, 0, 0);
    }
  }
#pragma unroll
  for (int ft = 0; ft < 2; ++ft)
#pragma unroll
    for (int r = 0; r < 4; ++r)
      cmb[w][4 * g + r][ft * 16 + cl] = acc[ft][r];
  __syncthreads();

  int row = t >> 4, c0 = t & 15;
  float v0 = cmb[0][row][c0] + cmb[1][row][c0] + cmb[2][row][c0] + cmb[3][row][c0];
  float v1 = cmb[0][row][c0 + 16] + cmb[1][row][c0 + 16] + cmb[2][row][c0 + 16] + cmb[3][row][c0 + 16];
  float ps = v0 * a2[c0] + v1 * a2[c0 + 16];
  float pd = v0 * a2[32 + c0] + v1 * a2[32 + c0 + 16];
  ps += __shfl_xor(ps, 1); ps += __shfl_xor(ps, 2); ps += __shfl_xor(ps, 4); ps += __shfl_xor(ps, 8);
  pd += __shfl_xor(pd, 1); pd += __shfl_xor(pd, 2); pd += __shfl_xor(pd, 4); pd += __shfl_xor(pd, 8);
  if (c0 == 0) {
    int idx = b * NN + rowbase + row;
    ssrc2[idx] = ps;
    G1o[idx] = __expf(pd);
    G2o[idx] = __expf(0.2f * pd);
  }
  cmb[0][row][c0] = v0;          // own location: read-then-write, no cross-thread hazard
  cmb[0][row][c0 + 16] = v1;
  __syncthreads();
  int col = t >> 3, rg = t & 7;  // transposed bf16 store, 2 nodes per thread
  unsigned pk = pk2(cmb[0][2 * rg][col], cmb[0][2 * rg + 1][col]);
  *(unsigned*)(wh2t + (size_t)(b * 32 + col) * NN + rowbase + 2 * rg) = pk;
}

// ---------- k4: layer-2 attention. block = 16 rows, 4 waves split columns ------
__global__ __launch_bounds__(256) void k4_attn2(
    const unsigned short* __restrict__ wh2t, const float* __restrict__ ssrc2,
    const float* __restrict__ G1o, const float* __restrict__ G2o,
    const unsigned* __restrict__ mb, float* __restrict__ outp) {
  __shared__ unsigned sdm[NW][16];     // 4 KB
  __shared__ float cmb[4][16][33];
  __shared__ float cmbd[4][16];
  int blk = blockIdx.x;                // 512: 16 rows each
  int b = blk >> 7, rowbase = (blk & 127) << 4;
  int t = threadIdx.x, lane = t & 63, w = t >> 6;
  int cl = lane & 15, g = lane >> 4;
  {
    int row = t >> 4, wb = (t & 15) * 4;
    uint4 v = *(const uint4*)(mb + (size_t)(b * NN + rowbase + row) * NW + wb);
    sdm[wb + 0][row] = v.x; sdm[wb + 1][row] = v.y;
    sdm[wb + 2][row] = v.z; sdm[wb + 3][row] = v.w;
  }
  const float* G1 = G1o + b * NN;
  const float* G2 = G2o + b * NN;
  float mxG = 0.f;
#pragma unroll
  for (int it = 0; it < 8; ++it) {
    f32x4 v = ((const f32x4*)G1)[it * 64 + lane];
    mxG = fmaxf(fmaxf(mxG, v[0]), fmaxf(v[1], fmaxf(v[2], v[3])));
  }
  mxG = fmaxf(mxG, __shfl_xor(mxG, 1));  mxG = fmaxf(mxG, __shfl_xor(mxG, 2));
  mxG = fmaxf(mxG, __shfl_xor(mxG, 4));  mxG = fmaxf(mxG, __shfl_xor(mxG, 8));
  mxG = fmaxf(mxG, __shfl_xor(mxG, 16)); mxG = fmaxf(mxG, __shfl_xor(mxG, 32));

  float s = ssrc2[b * NN + rowbase + cl];
  float m = lrelu(s + __logf(mxG));
  float F1 = __expf(s - m), F2 = __expf(0.2f * s - m), T = __expf(-s);
  __syncthreads();

  short onev = (cl == 0) ? (short)0x3F80 : (short)0;
  bf16x8 ones = {onev, onev, onev, onev, onev, onev, onev, onev};
  f32x4 zero = {0.f, 0.f, 0.f, 0.f};
  f32x4 acc[2] = {zero, zero};
  f32x4 acc1 = zero;
  const unsigned short* whb = wh2t + (size_t)(b * 32) * NN;

  for (int kb = w * 16; kb < w * 16 + 16; ++kb) {
    unsigned by = (sdm[kb][cl] >> (8 * g)) & 0xFFu;
    int j0 = kb * 32 + 8 * g;
    f32x4 g1a = *(const f32x4*)(G1 + j0);
    f32x4 g1b = *(const f32x4*)(G1 + j0 + 4);
    f32x4 g2a = *(const f32x4*)(G2 + j0);
    f32x4 g2b = *(const f32x4*)(G2 + j0 + 4);
    float wv[8];
#pragma unroll
    for (int e = 0; e < 8; ++e) {
      float g1 = (e < 4) ? g1a[e] : g1b[e - 4];
      float g2 = (e < 4) ? g2a[e] : g2b[e - 4];
      bool sg = g1 > T;
      float val = (sg ? F1 : F2) * (sg ? g1 : g2);
      wv[e] = ((by >> e) & 1u) ? val : 0.f;
    }
    union { unsigned u[4]; bf16x8 v; } pa;
    pa.u[0] = pk2(wv[0], wv[1]); pa.u[1] = pk2(wv[2], wv[3]);
    pa.u[2] = pk2(wv[4], wv[5]); pa.u[3] = pk2(wv[6], wv[7]);
#pragma unroll
    for (int ft = 0; ft < 2; ++ft) {
      bf16x8 bf = *(const bf16x8*)(whb + (size_t)(ft * 16 + cl) * NN + j0);
      acc[ft] = __builtin_amdgcn_mfma_f32_16x16x32_bf16(pa.v, bf, acc[ft], 0, 0, 0);
    }
    acc1 = __builtin_amdgcn_mfma_f32_16x16x32_bf16(pa.v, ones, acc1, 0, 0, 0);
  }
#pragma unroll
  for (int ft = 0; ft < 2; ++ft)
#pragma unroll
    for (int r = 0; r < 4; ++r)
      cmb[w][4 * g + r][ft * 16 + cl] = acc[ft][r];
  if (cl == 0) {
#pragma unroll
    for (int r = 0; r < 4; ++r) cmbd[w][4 * g + r] = acc1[r];
  }
  __syncthreads();
  int row = t >> 4, c0 = t & 15;
  float n0 = cmb[0][row][c0] + cmb[1][row][c0] + cmb[2][row][c0] + cmb[3][row][c0];
  float n1 = cmb[0][row][c0 + 16] + cmb[1][row][c0 + 16] + cmb[2][row][c0 + 16] + cmb[3][row][c0 + 16];
  float den = cmbd[0][row] + cmbd[1][row] + cmbd[2][row] + cmbd[3][row];
  float inv = 1.f / den;
  float* dst = outp + (size_t)(b * NN + rowbase + row) * 32;
  dst[c0] = n0 * inv;
  dst[c0 + 16] = n1 * inv;
}

extern "C" void kernel_launch(void* const* d_in, const int* in_sizes, int n_in,
                              void* d_out, int out_size, void* d_ws, size_t ws_size,
                              hipStream_t stream) {
  (void)in_sizes; (void)n_in; (void)out_size; (void)ws_size;
  const float* x   = (const float*)d_in[0];
  const int*   adj = (const int*)d_in[1];
  const float* W1  = (const float*)d_in[2];
  const float* a1  = (const float*)d_in[3];
  const float* W2  = (const float*)d_in[4];
  const float* a2  = (const float*)d_in[5];
  float* outp = (float*)d_out;
  char* ws = (char*)d_ws;

  unsigned*       mbits = (unsigned*)(ws);                                   // 2 MB
  unsigned short* wht1  = (unsigned short*)(ws + (size_t)(2u << 20));        // 4 MB
  float*          ssrc1 = (float*)(ws + (size_t)(6u << 20));                 // 128 KB
  float*          G1g   = (float*)(ws + (size_t)(6u << 20) + (128u << 10));  // 128 KB
  float*          G2g   = (float*)(ws + (size_t)(6u << 20) + (256u << 10));  // 128 KB
  float*          hbuf  = (float*)(ws + (size_t)(6u << 20) + (512u << 10));  // 8 MB
  unsigned short* wh2t  = (unsigned short*)(ws + (size_t)(14u << 20) + (512u << 10)); // 512 KB
  float*          ssrc2 = (float*)(ws + (size_t)(15u << 20));                // 32 KB
  float*          G1o   = (float*)(ws + (size_t)(15u << 20) + (32u << 10));  // 32 KB
  float*          G2o   = (float*)(ws + (size_t)(15u << 20) + (64u << 10));  // 32 KB

  kA      <<<16896, 256, 0, stream>>>(adj, mbits, x, W1, a1, wht1, ssrc1, G1g, G2g);
  k2_attn1<<<512,   256, 0, stream>>>(wht1, ssrc1, G1g, G2g, mbits, hbuf);
  k3_proj2<<<512,   256, 0, stream>>>(hbuf, W2, a2, wh2t, ssrc2, G1o, G2o);
  k4_attn2<<<512,   256, 0, stream>>>(wh2t, ssrc2, G1o, G2o, mbits, outp);
}